// Round 5
// baseline (198.957 us; speedup 1.0000x reference)
//
#include <hip/hip_runtime.h>

// ---------------------------------------------------------------------------
// GMMConv forward (ws budget: 25.6 MB — proven available since R2):
//  0) convert_inputs: Wp[j'][k]=bf16(W_fc[((j'&3)<<6)|(j'>>2)][k]) into a
//     128 KB overlay at the start of d_out (edge rewrites d_out afterwards);
//     Af = bf16(feat) into ws. One streaming pass (~77 MB).
//  1) gemm_inplace: nf = Af @ Wp.T IN PLACE over the same ws buffer.
//     Block = 64 rows x 256 cols (full J): reads only its own Af rows in the
//     K-loop, overwrites exactly those rows with nf in the epilogue (the last
//     block's row clamp min(row,M-1)=49999 stays inside its own row range,
//     so no cross-block read-after-write hazard). m97 recipe: 16B
//     global_load_lds staging, unpadded 64B LDS rows, 16x16x32 bf16 MFMA.
//  2) edge_aggregate: one wave per dst node (CSR rowptr sorts edges by dst,
//     no atomics). 128-thr blocks (2 nodes) to cut slowest-wave imbalance.
//     Cooperative gaussians in LDS; rolled gather loop (unroll-16 measured
//     worse in R3).
// ---------------------------------------------------------------------------

typedef __attribute__((ext_vector_type(8))) short bf16x8;
typedef __attribute__((ext_vector_type(4))) float f32x4;

__device__ inline unsigned short f32_to_bf16(float f) {
    union { float f; unsigned int u; } c; c.f = f;
    unsigned int u = c.u;
    u += 0x7fffu + ((u >> 16) & 1u);   // round-to-nearest-even
    return (unsigned short)(u >> 16);
}
__device__ inline float bf16_to_f32(unsigned short h) {
    union { unsigned int u; float f; } c; c.u = ((unsigned int)h) << 16;
    return c.f;
}
__device__ inline ushort4 cvt4(float4 v) {
    ushort4 h;
    h.x = f32_to_bf16(v.x); h.y = f32_to_bf16(v.y);
    h.z = f32_to_bf16(v.z); h.w = f32_to_bf16(v.w);
    return h;
}

// W permute+convert (first 16384 float4) + feat convert (grid-stride).
__global__ __launch_bounds__(256) void convert_inputs(
    const float* __restrict__ W, const float* __restrict__ feat,
    unsigned short* __restrict__ Wp, unsigned short* __restrict__ Af,
    int nFeat4)
{
    const int gid = blockIdx.x * 256 + threadIdx.x;
    if (gid < 16384) {
        const int jp = gid >> 6, k4 = gid & 63;
        const int wrow = ((jp & 3) << 6) | (jp >> 2);
        reinterpret_cast<ushort4*>(Wp)[jp * 64 + k4] =
            cvt4(reinterpret_cast<const float4*>(W)[wrow * 64 + k4]);
    }
    for (int i = gid; i < nFeat4; i += gridDim.x * 256)
        reinterpret_cast<ushort4*>(Af)[i] =
            cvt4(reinterpret_cast<const float4*>(feat)[i]);
}

// In-place: AC holds Af bf16 [M][256] on entry, nf bf16 [M][256] on exit.
// Block: 64 rows x 256 cols, 4 waves; wave w -> cols w*64..w*64+63.
__global__ __launch_bounds__(256) void gemm_inplace(
    unsigned short* AC,                     // aliases: A in, C out (same rows)
    const unsigned short* __restrict__ Wp,  // bf16 [256][256] permuted rows
    int M)
{
    __shared__ unsigned short As[64 * 32];   //  4 KB, 64 B/row (unpadded: DMA)
    __shared__ unsigned short Bs[256 * 32];  // 16 KB
    const int t    = threadIdx.x;
    const int lane = t & 63;
    const int wave = t >> 6;
    const int bm   = blockIdx.x * 64;
    const int l16  = lane & 15;
    const int quad = lane >> 4;
    const int wn   = wave * 64;

    // staging: lane l of a 1 KB chunk -> LDS byte l*16 == row l>>2, k (l&3)*8
    const int kc   = (lane & 3) * 8;
    const int arow = min(bm + wave * 16 + (lane >> 2), M - 1);  // own-block rows only
    const size_t asrc = (size_t)arow * 256 + kc;
    size_t bsrc[4];
#pragma unroll
    for (int j = 0; j < 4; ++j)
        bsrc[j] = (size_t)(wave * 64 + j * 16 + (lane >> 2)) * 256 + kc;

    f32x4 acc[4][4];
#pragma unroll
    for (int mi = 0; mi < 4; ++mi)
#pragma unroll
        for (int ni = 0; ni < 4; ++ni)
            acc[mi][ni] = (f32x4){0.f, 0.f, 0.f, 0.f};

    typedef __attribute__((address_space(3))) void lds_t;
    typedef const __attribute__((address_space(1))) void gm_t;

    for (int k0 = 0; k0 < 256; k0 += 32) {
        __builtin_amdgcn_global_load_lds((gm_t*)(AC + asrc + k0),
            (lds_t*)(As + wave * 512), 16, 0, 0);
#pragma unroll
        for (int j = 0; j < 4; ++j)
            __builtin_amdgcn_global_load_lds((gm_t*)(Wp + bsrc[j] + k0),
                (lds_t*)(Bs + (wave * 4 + j) * 512), 16, 0, 0);
        __syncthreads();

        bf16x8 af[4], bfr[4];
#pragma unroll
        for (int mi = 0; mi < 4; ++mi)
            af[mi] = *reinterpret_cast<const bf16x8*>(
                &As[(mi * 16 + l16) * 32 + quad * 8]);
#pragma unroll
        for (int ni = 0; ni < 4; ++ni)
            bfr[ni] = *reinterpret_cast<const bf16x8*>(
                &Bs[(wn + ni * 16 + l16) * 32 + quad * 8]);
#pragma unroll
        for (int mi = 0; mi < 4; ++mi)
#pragma unroll
            for (int ni = 0; ni < 4; ++ni)
                acc[mi][ni] = __builtin_amdgcn_mfma_f32_16x16x32_bf16(
                    af[mi], bfr[ni], acc[mi][ni], 0, 0, 0);
        __syncthreads();
    }

    // epilogue overwrites this block's own rows (all reads of them are done)
    // C/D layout: col = lane&15, row = quad*4 + reg   [m89-verified]
#pragma unroll
    for (int mi = 0; mi < 4; ++mi) {
#pragma unroll
        for (int r = 0; r < 4; ++r) {
            const int row = bm + mi * 16 + quad * 4 + r;
            if (row < M) {
#pragma unroll
                for (int ni = 0; ni < 4; ++ni) {
                    const int col = wn + ni * 16 + l16;
                    AC[(size_t)row * 256 + col] = f32_to_bf16(acc[mi][ni][r]);
                }
            }
        }
    }
}

// One wave per destination node; lane = feature f (F=64). 2 waves/block.
__global__ __launch_bounds__(128) void edge_aggregate(
    const int* __restrict__ rowptr,
    const int* __restrict__ colind,
    const float* __restrict__ pseudo,       // [E][2]
    const unsigned short* __restrict__ nf,  // bf16 [N][256] permuted [f*4+k]
    const float* __restrict__ mu,
    const float* __restrict__ inv_sigma,
    const float* __restrict__ bias,
    float* __restrict__ out,                // [N][64]
    int N)
{
    __shared__ float gbuf[2][64];
    __shared__ int   cbuf[2][16];
    const int wave = threadIdx.x >> 6;
    const int lane = threadIdx.x & 63;
    const int node = blockIdx.x * 2 + wave;
    if (node >= N) return;          // wave-uniform exit; no block barriers below

    const int kk = lane >> 4;
    const int ii = lane & 15;
    const float mx = mu[2 * kk], my = mu[2 * kk + 1];
    const float sa = inv_sigma[2 * kk], sb = inv_sigma[2 * kk + 1];
    const float sx = sa * sa, sy = sb * sb;

    const int e0 = rowptr[node];
    const int e1 = rowptr[node + 1];
    float* gw = gbuf[wave];
    int*   cw = cbuf[wave];

    float acc = 0.f;
    for (int ec = e0; ec < e1; ec += 16) {
        const int cnt = min(16, e1 - ec);
        if (ii < cnt) {
            const int e = ec + ii;
            const float2 p = *reinterpret_cast<const float2*>(pseudo + 2 * (size_t)e);
            const float dx = p.x - mx, dy = p.y - my;
            gw[ii * 4 + kk] = __expf(-0.5f * (dx * dx * sx + dy * dy * sy));
            if (kk == 0) cw[ii] = colind[e];
        }
        __builtin_amdgcn_wave_barrier();
        __threadfence_block();      // drain LDS writes before broadcast reads
        for (int i2 = 0; i2 < cnt; ++i2) {
            const int col = cw[i2];
            const float4 g = *reinterpret_cast<const float4*>(&gw[i2 * 4]);
            const ushort4 h = *reinterpret_cast<const ushort4*>(
                nf + ((size_t)col << 8) + (lane << 2));
            acc += g.x * bf16_to_f32(h.x) + g.y * bf16_to_f32(h.y)
                 + g.z * bf16_to_f32(h.z) + g.w * bf16_to_f32(h.w);
        }
        __builtin_amdgcn_wave_barrier();
        __threadfence_block();      // reads done before next chunk's writes
    }
    out[((size_t)node << 6) + lane] = acc + bias[lane];
}

extern "C" void kernel_launch(void* const* d_in, const int* in_sizes, int n_in,
                              void* d_out, int out_size, void* d_ws, size_t ws_size,
                              hipStream_t stream)
{
    const int*   rowptr    = (const int*)d_in[0];
    const int*   colind    = (const int*)d_in[1];
    // d_in[2] colptr, d_in[3] rowind, d_in[4] permute: inert in forward math
    const float* feat      = (const float*)d_in[5];
    const float* pseudo    = (const float*)d_in[6];
    const float* W_fc      = (const float*)d_in[7];
    const float* mu        = (const float*)d_in[8];
    const float* inv_sigma = (const float*)d_in[9];
    const float* bias      = (const float*)d_in[10];
    float* out = (float*)d_out;

    const int N = in_sizes[0] - 1;                 // 50000
    unsigned short* AC = (unsigned short*)d_ws;    // Af in / nf out, 25.6 MB
    unsigned short* Wp = (unsigned short*)d_out;   // 128 KB overlay; edge
                                                   // rewrites d_out afterwards

    hipLaunchKernelGGL(convert_inputs, dim3(1024), dim3(256), 0, stream,
                       W_fc, feat, Wp, AC, N * 64);

    hipLaunchKernelGGL(gemm_inplace, dim3((N + 63) / 64), dim3(256), 0, stream,
                       AC, Wp, N);

    hipLaunchKernelGGL(edge_aggregate, dim3((N + 1) / 2), dim3(128), 0, stream,
                       rowptr, colind, pseudo, AC, mu, inv_sigma, bias, out, N);
}